// Round 1
// baseline (111.698 us; speedup 1.0000x reference)
//
#include <hip/hip_runtime.h>

#define MDIM 4096
#define KDIM 2048
#define UDIM 1024
#define CMOFF (MDIM * UDIM)

typedef __bf16 bfrag __attribute__((ext_vector_type(8)));
typedef float f32x4 __attribute__((ext_vector_type(4)));

#define GLDS(gsrc, ldst)                                                                  \
  __builtin_amdgcn_global_load_lds((const __attribute__((address_space(1))) void*)(gsrc), \
                                   (__attribute__((address_space(3))) void*)(ldst), 16, 0, 0)

__device__ __forceinline__ unsigned short f2bf(float x) {
  unsigned int u = __float_as_uint(x);
  unsigned int r = (u + 0x7fffu + ((u >> 16) & 1u)) >> 16;
  return (unsigned short)r;
}

__device__ __forceinline__ float fast_sigmoid(float x) {
  return 1.f / (1.f + __expf(-x));
}

__device__ __forceinline__ float fast_tanh(float x) {
  float ax = fabsf(x);
  float e = __expf(-2.f * ax);
  float r = (1.f - e) / (1.f + e);
  return copysignf(r, x);
}

// Build A = [hidden | inputs] as bf16, row-major [4096][2048]
__global__ void pack_x(const float* __restrict__ hidden, const float* __restrict__ inputs,
                       unsigned short* __restrict__ A) {
  int t = blockIdx.x * blockDim.x + threadIdx.x;  // 0 .. 2M-1, 4 elems each
  int e = t * 4;
  int m = e >> 11;
  int c = e & 2047;
  const float* src = (c < 1024) ? (hidden + m * 1024 + c) : (inputs + m * 1024 + (c - 1024));
  float4 v = *(const float4*)src;
  ushort4 o;
  o.x = f2bf(v.x);
  o.y = f2bf(v.y);
  o.z = f2bf(v.z);
  o.w = f2bf(v.w);
  *(ushort4*)(A + e) = o;
}

// Transpose each W_g [2048][1024] f32 -> Wt rows [g*1024+u][k] bf16 ([4096][2048])
__global__ void pack_w(const float* __restrict__ Wf, const float* __restrict__ Wi,
                       const float* __restrict__ Wc, const float* __restrict__ Wo,
                       unsigned short* __restrict__ Wt) {
  __shared__ float tile[32][33];
  const int k0 = blockIdx.x * 32;
  const int u0 = blockIdx.y * 32;
  const int g = blockIdx.z;
  const float* W = (g == 0) ? Wf : (g == 1) ? Wi : (g == 2) ? Wc : Wo;
  const int t = threadIdx.x;
  {
    int kk = t >> 3, uu = (t & 7) * 4;
    float4 v = *(const float4*)(W + (k0 + kk) * UDIM + u0 + uu);
    tile[kk][uu + 0] = v.x;
    tile[kk][uu + 1] = v.y;
    tile[kk][uu + 2] = v.z;
    tile[kk][uu + 3] = v.w;
  }
  __syncthreads();
  {
    int ur = t >> 3, k4 = (t & 7) * 4;
    ushort4 o;
    o.x = f2bf(tile[k4 + 0][ur]);
    o.y = f2bf(tile[k4 + 1][ur]);
    o.z = f2bf(tile[k4 + 2][ur]);
    o.w = f2bf(tile[k4 + 3][ur]);
    *(ushort4*)(Wt + (size_t)(g * UDIM + u0 + ur) * KDIM + k0 + k4) = o;
  }
}

// Fused 4-gate GEMM + LSTM epilogue.
// Block tile: 128 rows (m) x [4 gates x 32 units]. 4 waves, each wave owns 32 rows x all 128 cols.
// A: [4096][2048] bf16 row-major. Wt: [4096][2048] bf16, row n = g*1024+u, n-major over K.
__global__ __launch_bounds__(256, 2) void lstm_gemm(
    const unsigned short* __restrict__ A, const unsigned short* __restrict__ Wt,
    const float* __restrict__ bf_, const float* __restrict__ bi_,
    const float* __restrict__ bc_, const float* __restrict__ bo_,
    const float* __restrict__ cell, float* __restrict__ out) {
  __shared__ __bf16 As[128][64];
  __shared__ __bf16 Bs[128][64];  // rows: q*32 + (u - u0), gate q

  const int m0 = blockIdx.x * 128;
  const int u0 = blockIdx.y * 32;
  const int t = threadIdx.x;
  const int lane = t & 63;
  const int w = t >> 6;
  const int lrow = lane & 15;         // A-row / B-col within fragment
  const int kblk = (lane >> 4) * 8;   // k offset within K=32 step

  f32x4 acc[2][8];
#pragma unroll
  for (int i = 0; i < 2; ++i)
#pragma unroll
    for (int j = 0; j < 8; ++j) acc[i][j] = (f32x4){0.f, 0.f, 0.f, 0.f};

  // staging addressing: thread t covers row q*32 + t/8, cols (t&7)*8 .. +8 of the [.][64] tile
  const int trow = t >> 3;
  const int tcol = (t & 7) * 8;
  const unsigned short* Ag = A + (size_t)(m0 + trow) * KDIM + tcol;
  const unsigned short* Bg = Wt + (size_t)(u0 + trow) * KDIM + tcol;  // + q*UDIM*KDIM per gate
  __bf16* AsL = &As[0][0] + t * 8;  // linear: wave-base + lane*16B
  __bf16* BsL = &Bs[0][0] + t * 8;

  for (int ks = 0; ks < KDIM; ks += 64) {
#pragma unroll
    for (int q = 0; q < 4; ++q) GLDS(Ag + (size_t)q * 32 * KDIM + ks, AsL + q * 2048);
#pragma unroll
    for (int q = 0; q < 4; ++q) GLDS(Bg + (size_t)q * UDIM * KDIM + ks, BsL + q * 2048);
    __syncthreads();
#pragma unroll
    for (int kk = 0; kk < 2; ++kk) {
      bfrag a0 = *(const bfrag*)&As[w * 32 + lrow][kk * 32 + kblk];
      bfrag a1 = *(const bfrag*)&As[w * 32 + 16 + lrow][kk * 32 + kblk];
#pragma unroll
      for (int nf = 0; nf < 8; ++nf) {
        bfrag b = *(const bfrag*)&Bs[nf * 16 + lrow][kk * 32 + kblk];
        acc[0][nf] = __builtin_amdgcn_mfma_f32_16x16x32_bf16(a0, b, acc[0][nf], 0, 0, 0);
        acc[1][nf] = __builtin_amdgcn_mfma_f32_16x16x32_bf16(a1, b, acc[1][nf], 0, 0, 0);
      }
    }
    __syncthreads();
  }

  // Epilogue: C/D layout col = lane&15, row = (lane>>4)*4 + reg  (m89-verified)
  const int rbase = m0 + w * 32 + (lane >> 4) * 4;
#pragma unroll
  for (int mi = 0; mi < 2; ++mi) {
#pragma unroll
    for (int uu = 0; uu < 2; ++uu) {
      const int u = u0 + uu * 16 + lrow;
      const float vbf = bf_[u];
      const float vbi = bi_[u];
      const float vbc = bc_[u];
      const float vbo = bo_[u];
#pragma unroll
      for (int j = 0; j < 4; ++j) {
        const int m = rbase + mi * 16 + j;
        float pf = acc[mi][0 + uu][j] + vbf;  // gate f: nf 0,1
        float pi = acc[mi][2 + uu][j] + vbi;  // gate i: nf 2,3
        float pc = acc[mi][4 + uu][j] + vbc;  // gate c: nf 4,5
        float po = acc[mi][6 + uu][j] + vbo;  // gate o: nf 6,7
        float fg = fast_sigmoid(pf);
        float ig = fast_sigmoid(pi);
        float cc = fast_tanh(pc);
        float og = fast_sigmoid(po);
        float cold = cell[m * UDIM + u];
        float cnew = fg * cold + ig * cc;
        float hnew = og * fast_tanh(cnew);
        out[m * UDIM + u] = hnew;
        out[CMOFF + m * UDIM + u] = cnew;
      }
    }
  }
}

extern "C" void kernel_launch(void* const* d_in, const int* in_sizes, int n_in,
                              void* d_out, int out_size, void* d_ws, size_t ws_size,
                              hipStream_t stream) {
  const float* inputs = (const float*)d_in[0];
  const float* hidden = (const float*)d_in[1];
  const float* cell = (const float*)d_in[2];
  const float* Wf = (const float*)d_in[3];
  const float* bf = (const float*)d_in[4];
  const float* Wi = (const float*)d_in[5];
  const float* bi = (const float*)d_in[6];
  const float* Wc = (const float*)d_in[7];
  const float* bc = (const float*)d_in[8];
  const float* Wo = (const float*)d_in[9];
  const float* bo = (const float*)d_in[10];
  float* out = (float*)d_out;

  unsigned short* Abf = (unsigned short*)d_ws;          // [4096][2048] bf16 = 16 MB
  unsigned short* Wt = Abf + (size_t)MDIM * KDIM;       // [4096][2048] bf16 = 16 MB

  pack_x<<<(MDIM * KDIM / 4) / 256, 256, 0, stream>>>(hidden, inputs, Abf);
  pack_w<<<dim3(KDIM / 32, UDIM / 32, 4), 256, 0, stream>>>(Wf, Wi, Wc, Wo, Wt);
  lstm_gemm<<<dim3(MDIM / 128, UDIM / 32), 256, 0, stream>>>(Abf, Wt, bf, bi, bc, bo, cell, out);
}

// Round 2
// 92.341 us; speedup vs baseline: 1.2096x; 1.2096x over previous
//
#include <hip/hip_runtime.h>

#define MDIM 4096
#define KDIM 2048
#define UDIM 1024
#define CMOFF (MDIM * UDIM)
#define NK 64  // KDIM / 32
#define THREADS 512

typedef __bf16 bfrag __attribute__((ext_vector_type(8)));
typedef float f32x4 __attribute__((ext_vector_type(4)));

#define GLDS(gsrc, ldst)                                                                  \
  __builtin_amdgcn_global_load_lds((const __attribute__((address_space(1))) void*)(gsrc), \
                                   (__attribute__((address_space(3))) void*)(ldst), 16, 0, 0)

__device__ __forceinline__ unsigned short f2bf(float x) {
  unsigned int u = __float_as_uint(x);
  unsigned int r = (u + 0x7fffu + ((u >> 16) & 1u)) >> 16;
  return (unsigned short)r;
}

__device__ __forceinline__ float fast_sigmoid(float x) { return 1.f / (1.f + __expf(-x)); }

__device__ __forceinline__ float fast_tanh(float x) {
  float ax = fabsf(x);
  float e = __expf(-2.f * ax);
  float r = (1.f - e) / (1.f + e);
  return copysignf(r, x);
}

// Build A = [hidden | inputs] as bf16, row-major [4096][2048]
__global__ void pack_x(const float* __restrict__ hidden, const float* __restrict__ inputs,
                       unsigned short* __restrict__ A) {
  int t = blockIdx.x * blockDim.x + threadIdx.x;
  int e = t * 4;
  int m = e >> 11;
  int c = e & 2047;
  const float* src = (c < 1024) ? (hidden + m * 1024 + c) : (inputs + m * 1024 + (c - 1024));
  float4 v = *(const float4*)src;
  ushort4 o;
  o.x = f2bf(v.x);
  o.y = f2bf(v.y);
  o.z = f2bf(v.z);
  o.w = f2bf(v.w);
  *(ushort4*)(A + e) = o;
}

// Transpose each W_g [2048][1024] f32 -> Wt rows [g*1024+u][k] bf16 ([4096][2048])
__global__ void pack_w(const float* __restrict__ Wf, const float* __restrict__ Wi,
                       const float* __restrict__ Wc, const float* __restrict__ Wo,
                       unsigned short* __restrict__ Wt) {
  __shared__ float tile[32][33];
  const int k0 = blockIdx.x * 32;
  const int u0 = blockIdx.y * 32;
  const int g = blockIdx.z;
  const float* W = (g == 0) ? Wf : (g == 1) ? Wi : (g == 2) ? Wc : Wo;
  const int t = threadIdx.x;
  {
    int kk = t >> 3, uu = (t & 7) * 4;
    float4 v = *(const float4*)(W + (k0 + kk) * UDIM + u0 + uu);
    tile[kk][uu + 0] = v.x;
    tile[kk][uu + 1] = v.y;
    tile[kk][uu + 2] = v.z;
    tile[kk][uu + 3] = v.w;
  }
  __syncthreads();
  {
    int ur = t >> 3, k4 = (t & 7) * 4;
    ushort4 o;
    o.x = f2bf(tile[k4 + 0][ur]);
    o.y = f2bf(tile[k4 + 1][ur]);
    o.z = f2bf(tile[k4 + 2][ur]);
    o.w = f2bf(tile[k4 + 3][ur]);
    *(ushort4*)(Wt + (size_t)(g * UDIM + u0 + ur) * KDIM + k0 + k4) = o;
  }
}

// Fused 4-gate GEMM + LSTM epilogue, 8-phase-style schedule.
// 256(M) x 256(N: 64 units x 4 gates) tile, BK=32, 4-deep LDS K-tile ring,
// counted vmcnt(8) (2 K-tiles always in flight), granule-XOR LDS swizzle.
// 8 waves = 2(M) x 4(N). Per wave: 8 mi x 4 nf fragments (128 x 64 output).
__global__ __launch_bounds__(THREADS, 2) void lstm_gemm(
    const unsigned short* __restrict__ A, const unsigned short* __restrict__ Wt,
    const float* __restrict__ bf_, const float* __restrict__ bi_,
    const float* __restrict__ bc_, const float* __restrict__ bo_,
    const float* __restrict__ cell, float* __restrict__ out) {
  extern __shared__ __bf16 lds[];  // 4 rings x (A: 256*32 + B: 256*32) = 65536 elems = 128 KiB

  const int tid = threadIdx.x;
  const int lane = tid & 63;
  const int wid = tid >> 6;
  const int wr = wid >> 2;   // M-half of block
  const int wc = wid & 3;    // N quarter
  const int lrow = lane & 15;
  const int gb = lane >> 4;  // k-granule (16B) index within 64B row

  // bijective XCD swizzle over exactly 256 workgroups (1 per CU)
  const int wg = blockIdx.x;
  const int swz = (wg & 7) * 32 + (wg >> 3);
  const int m0 = (swz >> 4) * 256;
  const int bn = swz & 15;  // 64-unit block

  // ---- staging source pointers (inverse-swizzled global addresses) ----
  // LDS linear granule G holds: row = G>>2, source-granule = (G&3) ^ ((row>>1)&3)
  const int G0 = tid, G1 = THREADS + tid;
  const int ar0 = G0 >> 2, ar1 = G1 >> 2;
  const unsigned short* aS0 =
      A + (size_t)(m0 + ar0) * KDIM + (((G0 & 3) ^ ((ar0 >> 1) & 3)) * 8);
  const unsigned short* aS1 =
      A + (size_t)(m0 + ar1) * KDIM + (((G1 & 3) ^ ((ar1 >> 1) & 3)) * 8);
  // B LDS row n in [0,256): gate g=(n>>4)&3, unit u = bn*64 + (n>>6)*16 + (n&15)
  const int nr0 = G0 >> 2, nr1 = G1 >> 2;
  const int u_0 = bn * 64 + ((nr0 >> 6) << 4) + (nr0 & 15);
  const int u_1 = bn * 64 + ((nr1 >> 6) << 4) + (nr1 & 15);
  const int g_0 = (nr0 >> 4) & 3;
  const int g_1 = (nr1 >> 4) & 3;
  const unsigned short* bS0 =
      Wt + (size_t)(g_0 * UDIM + u_0) * KDIM + (((G0 & 3) ^ ((nr0 >> 1) & 3)) * 8);
  const unsigned short* bS1 =
      Wt + (size_t)(g_1 * UDIM + u_1) * KDIM + (((G1 & 3) ^ ((nr1 >> 1) & 3)) * 8);

  // ---- fragment read offsets (elems, without ring base), swizzled ----
  int aoff[8];
#pragma unroll
  for (int mi = 0; mi < 8; ++mi) {
    const int R = wr * 128 + mi * 16 + lrow;
    aoff[mi] = R * 32 + ((gb ^ ((R >> 1) & 3)) * 8);
  }
  int boff[4];
#pragma unroll
  for (int nf = 0; nf < 4; ++nf) {
    const int n = wc * 64 + nf * 16 + lrow;
    boff[nf] = 8192 + n * 32 + ((gb ^ ((n >> 1) & 3)) * 8);
  }

  f32x4 acc[8][4];
#pragma unroll
  for (int mi = 0; mi < 8; ++mi)
#pragma unroll
    for (int nf = 0; nf < 4; ++nf) acc[mi][nf] = (f32x4){0.f, 0.f, 0.f, 0.f};

#define STAGE_A(T)                                     \
  do {                                                 \
    __bf16* dst_ = lds + ((T) & 3) * 16384;            \
    GLDS(aS0 + (T) * 32, dst_ + G0 * 8);               \
    GLDS(aS1 + (T) * 32, dst_ + G1 * 8);               \
  } while (0)
#define STAGE_B(T)                                     \
  do {                                                 \
    __bf16* dst_ = lds + ((T) & 3) * 16384 + 8192;     \
    GLDS(bS0 + (T) * 32, dst_ + G0 * 8);               \
    GLDS(bS1 + (T) * 32, dst_ + G1 * 8);               \
  } while (0)

  // prologue: rings 0,1,2 in flight; wait ring 0 (8 = rings 1,2 outstanding)
  STAGE_A(0);
  STAGE_B(0);
  STAGE_A(1);
  STAGE_B(1);
  STAGE_A(2);
  STAGE_B(2);
  __builtin_amdgcn_sched_barrier(0);
  asm volatile("s_waitcnt vmcnt(8)" ::: "memory");
  __builtin_amdgcn_s_barrier();
  __builtin_amdgcn_sched_barrier(0);

#define TILE_BODY(T, DO_STAGE, WAITCODE)                                                       \
  do {                                                                                         \
    __bf16* ldsr_ = lds + ((T) & 3) * 16384;                                                   \
    bfrag Af[8];                                                                               \
    _Pragma("unroll") for (int mi = 0; mi < 8; ++mi) Af[mi] = *(const bfrag*)(ldsr_ + aoff[mi]); \
    bfrag Bf0 = *(const bfrag*)(ldsr_ + boff[0]);                                              \
    bfrag Bf1 = *(const bfrag*)(ldsr_ + boff[1]);                                              \
    if (DO_STAGE) STAGE_A((T) + 3);                                                            \
    __builtin_amdgcn_sched_barrier(0);                                                         \
    __builtin_amdgcn_s_barrier();                                                              \
    __builtin_amdgcn_sched_barrier(0);                                                         \
    __builtin_amdgcn_s_setprio(1);                                                             \
    _Pragma("unroll") for (int mi = 0; mi < 8; ++mi) acc[mi][0] =                              \
        __builtin_amdgcn_mfma_f32_16x16x32_bf16(Af[mi], Bf0, acc[mi][0], 0, 0, 0);             \
    _Pragma("unroll") for (int mi = 0; mi < 8; ++mi) acc[mi][1] =                              \
        __builtin_amdgcn_mfma_f32_16x16x32_bf16(Af[mi], Bf1, acc[mi][1], 0, 0, 0);             \
    __builtin_amdgcn_s_setprio(0);                                                             \
    __builtin_amdgcn_sched_barrier(0);                                                         \
    __builtin_amdgcn_s_barrier();                                                              \
    __builtin_amdgcn_sched_barrier(0);                                                         \
    bfrag Bf2 = *(const bfrag*)(ldsr_ + boff[2]);                                              \
    bfrag Bf3 = *(const bfrag*)(ldsr_ + boff[3]);                                              \
    if (DO_STAGE) STAGE_B((T) + 3);                                                            \
    __builtin_amdgcn_sched_barrier(0);                                                         \
    __builtin_amdgcn_s_barrier();                                                              \
    __builtin_amdgcn_sched_barrier(0);                                                         \
    __builtin_amdgcn_s_setprio(1);                                                             \
    _Pragma("unroll") for (int mi = 0; mi < 8; ++mi) acc[mi][2] =                              \
        __builtin_amdgcn_mfma_f32_16x16x32_bf16(Af[mi], Bf2, acc[mi][2], 0, 0, 0);             \
    _Pragma("unroll") for (int mi = 0; mi < 8; ++mi) acc[mi][3] =                              \
        __builtin_amdgcn_mfma_f32_16x16x32_bf16(Af[mi], Bf3, acc[mi][3], 0, 0, 0);             \
    __builtin_amdgcn_s_setprio(0);                                                             \
    __builtin_amdgcn_sched_barrier(0);                                                         \
    WAITCODE;                                                                                  \
    __builtin_amdgcn_s_barrier();                                                              \
    __builtin_amdgcn_sched_barrier(0);                                                         \
  } while (0)

  for (int t = 0; t <= NK - 4; ++t) {
    TILE_BODY(t, 1, asm volatile("s_waitcnt vmcnt(8)" ::: "memory"));
  }
  TILE_BODY(NK - 3, 0, asm volatile("s_waitcnt vmcnt(4)" ::: "memory"));
  TILE_BODY(NK - 2, 0, asm volatile("s_waitcnt vmcnt(0)" ::: "memory"));
  TILE_BODY(NK - 1, 0, );

  // ---- epilogue: per lane, 4 nf-fragments = the 4 gates of one unit u ----
  const int u = bn * 64 + wc * 16 + lrow;
  const float fb = bf_[u], ib = bi_[u], cb = bc_[u], ob = bo_[u];
  const int rbase = m0 + wr * 128 + (lane >> 4) * 4;
#pragma unroll
  for (int mi = 0; mi < 8; ++mi) {
#pragma unroll
    for (int j = 0; j < 4; ++j) {
      const int m = rbase + mi * 16 + j;
      float pf = acc[mi][0][j] + fb;
      float pi = acc[mi][1][j] + ib;
      float pc = acc[mi][2][j] + cb;
      float po = acc[mi][3][j] + ob;
      float fg = fast_sigmoid(pf);
      float ig = fast_sigmoid(pi);
      float cc = fast_tanh(pc);
      float og = fast_sigmoid(po);
      float cold = cell[(size_t)m * UDIM + u];
      float cnew = fg * cold + ig * cc;
      out[(size_t)m * UDIM + u] = og * fast_tanh(cnew);
      out[CMOFF + (size_t)m * UDIM + u] = cnew;
    }
  }
}

extern "C" void kernel_launch(void* const* d_in, const int* in_sizes, int n_in,
                              void* d_out, int out_size, void* d_ws, size_t ws_size,
                              hipStream_t stream) {
  const float* inputs = (const float*)d_in[0];
  const float* hidden = (const float*)d_in[1];
  const float* cell = (const float*)d_in[2];
  const float* Wf = (const float*)d_in[3];
  const float* bf = (const float*)d_in[4];
  const float* Wi = (const float*)d_in[5];
  const float* bi = (const float*)d_in[6];
  const float* Wc = (const float*)d_in[7];
  const float* bc = (const float*)d_in[8];
  const float* Wo = (const float*)d_in[9];
  const float* bo = (const float*)d_in[10];
  float* out = (float*)d_out;

  unsigned short* Abf = (unsigned short*)d_ws;     // [4096][2048] bf16 = 16 MB
  unsigned short* Wt = Abf + (size_t)MDIM * KDIM;  // [4096][2048] bf16 = 16 MB

  pack_x<<<(MDIM * KDIM / 4) / 256, 256, 0, stream>>>(hidden, inputs, Abf);
  pack_w<<<dim3(KDIM / 32, UDIM / 32, 4), 256, 0, stream>>>(Wf, Wi, Wc, Wo, Wt);
  lstm_gemm<<<dim3(256), dim3(THREADS), 131072, stream>>>(Abf, Wt, bf, bi, bc, bo, cell, out);
}

// Round 3
// 89.819 us; speedup vs baseline: 1.2436x; 1.0281x over previous
//
#include <hip/hip_runtime.h>

#define MDIM 4096
#define KDIM 2048
#define UDIM 1024
#define CMOFF (MDIM * UDIM)
#define NK 64  // KDIM / 32
#define THREADS 512

typedef __bf16 bfrag __attribute__((ext_vector_type(8)));
typedef float f32x4 __attribute__((ext_vector_type(4)));

#define GLDS(gsrc, ldst)                                                                  \
  __builtin_amdgcn_global_load_lds((const __attribute__((address_space(1))) void*)(gsrc), \
                                   (__attribute__((address_space(3))) void*)(ldst), 16, 0, 0)

__device__ __forceinline__ unsigned short f2bf(float x) {
  unsigned int u = __float_as_uint(x);
  unsigned int r = (u + 0x7fffu + ((u >> 16) & 1u)) >> 16;
  return (unsigned short)r;
}

__device__ __forceinline__ float fast_sigmoid(float x) { return 1.f / (1.f + __expf(-x)); }

__device__ __forceinline__ float fast_tanh(float x) {
  float ax = fabsf(x);
  float e = __expf(-2.f * ax);
  float r = (1.f - e) / (1.f + e);
  return copysignf(r, x);
}

// Build A = [hidden | inputs] as bf16, row-major [4096][2048]
__global__ void pack_x(const float* __restrict__ hidden, const float* __restrict__ inputs,
                       unsigned short* __restrict__ A) {
  int t = blockIdx.x * blockDim.x + threadIdx.x;
  int e = t * 4;
  int m = e >> 11;
  int c = e & 2047;
  const float* src = (c < 1024) ? (hidden + m * 1024 + c) : (inputs + m * 1024 + (c - 1024));
  float4 v = *(const float4*)src;
  ushort4 o;
  o.x = f2bf(v.x);
  o.y = f2bf(v.y);
  o.z = f2bf(v.z);
  o.w = f2bf(v.w);
  *(ushort4*)(A + e) = o;
}

// Transpose each W_g [2048][1024] f32 -> Wt rows [g*1024+u][k] bf16 ([4096][2048])
__global__ void pack_w(const float* __restrict__ Wf, const float* __restrict__ Wi,
                       const float* __restrict__ Wc, const float* __restrict__ Wo,
                       unsigned short* __restrict__ Wt) {
  __shared__ float tile[32][33];
  const int k0 = blockIdx.x * 32;
  const int u0 = blockIdx.y * 32;
  const int g = blockIdx.z;
  const float* W = (g == 0) ? Wf : (g == 1) ? Wi : (g == 2) ? Wc : Wo;
  const int t = threadIdx.x;
  {
    int kk = t >> 3, uu = (t & 7) * 4;
    float4 v = *(const float4*)(W + (k0 + kk) * UDIM + u0 + uu);
    tile[kk][uu + 0] = v.x;
    tile[kk][uu + 1] = v.y;
    tile[kk][uu + 2] = v.z;
    tile[kk][uu + 3] = v.w;
  }
  __syncthreads();
  {
    int ur = t >> 3, k4 = (t & 7) * 4;
    ushort4 o;
    o.x = f2bf(tile[k4 + 0][ur]);
    o.y = f2bf(tile[k4 + 1][ur]);
    o.z = f2bf(tile[k4 + 2][ur]);
    o.w = f2bf(tile[k4 + 3][ur]);
    *(ushort4*)(Wt + (size_t)(g * UDIM + u0 + ur) * KDIM + k0 + k4) = o;
  }
}

// Fused 4-gate GEMM + LSTM epilogue.
// 256(M) x 256(N: 64 units x 4 gates) tile, BK=32, 4-deep LDS K-tile ring,
// counted vmcnt(8) once per tile (2 K-tiles always in flight), granule-XOR swizzle.
// 8 waves = 2(M) x 4(N). Per wave: 8 mi x 4 nf fragments (128 x 64 output).
// Per tile: P1 {8 ds_read (A0-3,B0-3), stage-A, barrier, 16 MFMA},
//           P2 {4 ds_read (A4-7), stage-B, barrier, 16 MFMA, vmcnt(8), barrier}.
// No sched_barrier walls: correctness = data deps + vmcnt memory-clobber fences.
__global__ __launch_bounds__(THREADS, 2) void lstm_gemm(
    const unsigned short* __restrict__ A, const unsigned short* __restrict__ Wt,
    const float* __restrict__ bf_, const float* __restrict__ bi_,
    const float* __restrict__ bc_, const float* __restrict__ bo_,
    const float* __restrict__ cell, float* __restrict__ out) {
  extern __shared__ __bf16 lds[];  // 4 rings x (A: 256*32 + B: 256*32) = 128 KiB

  const int tid = threadIdx.x;
  const int lane = tid & 63;
  const int wid = tid >> 6;
  const int wr = wid >> 2;   // M-half of block
  const int wc = wid & 3;    // N quarter
  const int lrow = lane & 15;
  const int gb = lane >> 4;  // k-granule (16B) index within 64B row

  // bijective XCD swizzle over exactly 256 workgroups (1 per CU)
  const int wg = blockIdx.x;
  const int swz = (wg & 7) * 32 + (wg >> 3);
  const int m0 = (swz >> 4) * 256;
  const int bn = swz & 15;  // 64-unit block

  // ---- staging source pointers (inverse-swizzled global addresses) ----
  // LDS linear granule G holds: row = G>>2, source-granule = (G&3) ^ ((row>>1)&3)
  const int G0 = tid, G1 = THREADS + tid;
  const int ar0 = G0 >> 2, ar1 = G1 >> 2;
  const unsigned short* aS0 =
      A + (size_t)(m0 + ar0) * KDIM + (((G0 & 3) ^ ((ar0 >> 1) & 3)) * 8);
  const unsigned short* aS1 =
      A + (size_t)(m0 + ar1) * KDIM + (((G1 & 3) ^ ((ar1 >> 1) & 3)) * 8);
  // B LDS row n in [0,256): gate g=(n>>4)&3, unit u = bn*64 + (n>>6)*16 + (n&15)
  const int nr0 = G0 >> 2, nr1 = G1 >> 2;
  const int u_0 = bn * 64 + ((nr0 >> 6) << 4) + (nr0 & 15);
  const int u_1 = bn * 64 + ((nr1 >> 6) << 4) + (nr1 & 15);
  const int g_0 = (nr0 >> 4) & 3;
  const int g_1 = (nr1 >> 4) & 3;
  const unsigned short* bS0 =
      Wt + (size_t)(g_0 * UDIM + u_0) * KDIM + (((G0 & 3) ^ ((nr0 >> 1) & 3)) * 8);
  const unsigned short* bS1 =
      Wt + (size_t)(g_1 * UDIM + u_1) * KDIM + (((G1 & 3) ^ ((nr1 >> 1) & 3)) * 8);

  // ---- fragment read offsets (elems, without ring base), swizzled ----
  int aoff[8];
#pragma unroll
  for (int mi = 0; mi < 8; ++mi) {
    const int R = wr * 128 + mi * 16 + lrow;
    aoff[mi] = R * 32 + ((gb ^ ((R >> 1) & 3)) * 8);
  }
  int boff[4];
#pragma unroll
  for (int nf = 0; nf < 4; ++nf) {
    const int n = wc * 64 + nf * 16 + lrow;
    boff[nf] = 8192 + n * 32 + ((gb ^ ((n >> 1) & 3)) * 8);
  }

  f32x4 acc[8][4];
#pragma unroll
  for (int mi = 0; mi < 8; ++mi)
#pragma unroll
    for (int nf = 0; nf < 4; ++nf) acc[mi][nf] = (f32x4){0.f, 0.f, 0.f, 0.f};

#define STAGE_A(T, SR)                        \
  do {                                        \
    __bf16* dst_ = lds + (SR) * 16384;        \
    GLDS(aS0 + (T) * 32, dst_ + G0 * 8);      \
    GLDS(aS1 + (T) * 32, dst_ + G1 * 8);      \
  } while (0)
#define STAGE_B(T, SR)                        \
  do {                                        \
    __bf16* dst_ = lds + (SR) * 16384 + 8192; \
    GLDS(bS0 + (T) * 32, dst_ + G0 * 8);      \
    GLDS(bS1 + (T) * 32, dst_ + G1 * 8);      \
  } while (0)

  // prologue: rings 0,1,2 in flight; vmcnt(8) -> ring 0 landed
  STAGE_A(0, 0);
  STAGE_B(0, 0);
  STAGE_A(1, 1);
  STAGE_B(1, 1);
  STAGE_A(2, 2);
  STAGE_B(2, 2);
  asm volatile("s_waitcnt vmcnt(8)" ::: "memory");
  __builtin_amdgcn_s_barrier();

#define TILE_BODY(T, R, SR, DO_STAGE, WAITCODE)                                        \
  do {                                                                                 \
    __bf16* ldsr_ = lds + (R) * 16384;                                                 \
    bfrag Am[4], Bm[4];                                                                \
    _Pragma("unroll") for (int mi = 0; mi < 4; ++mi) Am[mi] =                          \
        *(const bfrag*)(ldsr_ + aoff[mi]);                                             \
    _Pragma("unroll") for (int nf = 0; nf < 4; ++nf) Bm[nf] =                          \
        *(const bfrag*)(ldsr_ + boff[nf]);                                             \
    if (DO_STAGE) STAGE_A((T) + 3, SR);                                                \
    __builtin_amdgcn_s_barrier();                                                      \
    __builtin_amdgcn_s_setprio(1);                                                     \
    _Pragma("unroll") for (int mi = 0; mi < 4; ++mi)                                   \
        _Pragma("unroll") for (int nf = 0; nf < 4; ++nf) acc[mi][nf] =                 \
            __builtin_amdgcn_mfma_f32_16x16x32_bf16(Am[mi], Bm[nf], acc[mi][nf], 0, 0, 0); \
    __builtin_amdgcn_s_setprio(0);                                                     \
    bfrag A2[4];                                                                       \
    _Pragma("unroll") for (int mi = 0; mi < 4; ++mi) A2[mi] =                          \
        *(const bfrag*)(ldsr_ + aoff[4 + mi]);                                         \
    if (DO_STAGE) STAGE_B((T) + 3, SR);                                                \
    __builtin_amdgcn_s_barrier();                                                      \
    __builtin_amdgcn_s_setprio(1);                                                     \
    _Pragma("unroll") for (int mi = 0; mi < 4; ++mi)                                   \
        _Pragma("unroll") for (int nf = 0; nf < 4; ++nf) acc[4 + mi][nf] =             \
            __builtin_amdgcn_mfma_f32_16x16x32_bf16(A2[mi], Bm[nf], acc[4 + mi][nf], 0, 0, 0); \
    __builtin_amdgcn_s_setprio(0);                                                     \
    WAITCODE;                                                                          \
    __builtin_amdgcn_s_barrier();                                                      \
  } while (0)

#define VM8 asm volatile("s_waitcnt vmcnt(8)" ::: "memory")
#define VM4 asm volatile("s_waitcnt vmcnt(4)" ::: "memory")
#define VM0 asm volatile("s_waitcnt vmcnt(0)" ::: "memory")

  for (int t = 0; t < NK - 4; t += 4) {  // t = 0,4,...,56 ; tiles 0..59, stages 3..62
    TILE_BODY(t + 0, 0, 3, 1, VM8);
    TILE_BODY(t + 1, 1, 0, 1, VM8);
    TILE_BODY(t + 2, 2, 1, 1, VM8);
    TILE_BODY(t + 3, 3, 2, 1, VM8);
  }
  TILE_BODY(NK - 4, 0, 3, 1, VM8);  // tile 60, stages tile 63 into ring 3
  TILE_BODY(NK - 3, 1, 0, 0, VM4);  // tile 61
  TILE_BODY(NK - 2, 2, 0, 0, VM0);  // tile 62
  TILE_BODY(NK - 1, 3, 0, 0, );     // tile 63

  // ---- epilogue: per lane, 4 nf-fragments = the 4 gates of one unit u ----
  const int u = bn * 64 + wc * 16 + lrow;
  const float fb = bf_[u], ib = bi_[u], cb = bc_[u], ob = bo_[u];
  const int rbase = m0 + wr * 128 + (lane >> 4) * 4;
#pragma unroll
  for (int mi = 0; mi < 8; ++mi) {
#pragma unroll
    for (int j = 0; j < 4; ++j) {
      const int m = rbase + mi * 16 + j;
      float pf = acc[mi][0][j] + fb;
      float pi = acc[mi][1][j] + ib;
      float pc = acc[mi][2][j] + cb;
      float po = acc[mi][3][j] + ob;
      float fg = fast_sigmoid(pf);
      float ig = fast_sigmoid(pi);
      float cc = fast_tanh(pc);
      float og = fast_sigmoid(po);
      float cold = cell[(size_t)m * UDIM + u];
      float cnew = fg * cold + ig * cc;
      out[(size_t)m * UDIM + u] = og * fast_tanh(cnew);
      out[CMOFF + (size_t)m * UDIM + u] = cnew;
    }
  }
}

extern "C" void kernel_launch(void* const* d_in, const int* in_sizes, int n_in,
                              void* d_out, int out_size, void* d_ws, size_t ws_size,
                              hipStream_t stream) {
  const float* inputs = (const float*)d_in[0];
  const float* hidden = (const float*)d_in[1];
  const float* cell = (const float*)d_in[2];
  const float* Wf = (const float*)d_in[3];
  const float* bf = (const float*)d_in[4];
  const float* Wi = (const float*)d_in[5];
  const float* bi = (const float*)d_in[6];
  const float* Wc = (const float*)d_in[7];
  const float* bc = (const float*)d_in[8];
  const float* Wo = (const float*)d_in[9];
  const float* bo = (const float*)d_in[10];
  float* out = (float*)d_out;

  unsigned short* Abf = (unsigned short*)d_ws;     // [4096][2048] bf16 = 16 MB
  unsigned short* Wt = Abf + (size_t)MDIM * KDIM;  // [4096][2048] bf16 = 16 MB

  pack_x<<<(MDIM * KDIM / 4) / 256, 256, 0, stream>>>(hidden, inputs, Abf);
  pack_w<<<dim3(KDIM / 32, UDIM / 32, 4), 256, 0, stream>>>(Wf, Wi, Wc, Wo, Wt);
  lstm_gemm<<<dim3(256), dim3(THREADS), 131072, stream>>>(Abf, Wt, bf, bi, bc, bo, cell, out);
}